// Round 11
// baseline (587.777 us; speedup 1.0000x reference)
//
#include <hip/hip_runtime.h>
#include <math.h>

#define T 2048
#define D 512
#define NH 8
#define DH 64
#define NL 4

typedef float f32x4 __attribute__((ext_vector_type(4)));
typedef short bf16x8 __attribute__((ext_vector_type(8)));
typedef unsigned short u16x4 __attribute__((ext_vector_type(4)));
typedef unsigned int u32x4 __attribute__((ext_vector_type(4)));
typedef unsigned short ushort_t;

#define MODE_F32 0
#define MODE_BF16_GELU 1

__device__ inline ushort_t f2bf(float x) {
    unsigned int u = __float_as_uint(x);
    unsigned int r = (u + 0x7FFFu + ((u >> 16) & 1u)) >> 16;  // RNE
    return (ushort_t)r;
}

__global__ void add_pos_kernel(const float* __restrict__ seq,
                               const float* __restrict__ pos,
                               float* __restrict__ x, int n) {
    int i = blockIdx.x * blockDim.x + threadIdx.x;
    if (i < n) x[i] = seq[i] + pos[i];
}

// Tiled transpose+convert: W[z·wZ + K×N] fp32 -> Wt[z·dZ + N×K] bf16.
__global__ __launch_bounds__(256) void wt_kernel(
    const float* __restrict__ W, ushort_t* __restrict__ Wt, int K, int N,
    size_t wZ, size_t dZ) {
    __shared__ float tile[32][33];
    int tx = threadIdx.x & 31, ty = threadIdx.x >> 5;  // 32 x 8
    const float* Wz = W + (size_t)blockIdx.z * wZ;
    ushort_t* Wtz = Wt + (size_t)blockIdx.z * dZ;
    int n0 = blockIdx.x * 32, k0 = blockIdx.y * 32;
    #pragma unroll
    for (int i = 0; i < 4; ++i)
        tile[ty + i * 8][tx] = Wz[(size_t)(k0 + ty + i * 8) * N + n0 + tx];
    __syncthreads();
    #pragma unroll
    for (int i = 0; i < 4; ++i)
        Wtz[(size_t)(n0 + ty + i * 8) * K + k0 + tx] = f2bf(tile[tx][ty + i * 8]);
}

// One block (256 threads) per row; writes bf16.
__global__ __launch_bounds__(256) void layernorm_kernel(
    const float* __restrict__ x, const float* __restrict__ w,
    const float* __restrict__ b, ushort_t* __restrict__ out) {
    int row = blockIdx.x;
    int tid = threadIdx.x;
    const float* xr = x + (size_t)row * D;
    float v0 = xr[tid];
    float v1 = xr[tid + 256];
    __shared__ float red[256];
    red[tid] = v0 + v1;
    __syncthreads();
    for (int off = 128; off > 0; off >>= 1) {
        if (tid < off) red[tid] += red[tid + off];
        __syncthreads();
    }
    float mu = red[0] * (1.0f / D);
    __syncthreads();
    float d0 = v0 - mu, d1 = v1 - mu;
    red[tid] = d0 * d0 + d1 * d1;
    __syncthreads();
    for (int off = 128; off > 0; off >>= 1) {
        if (tid < off) red[tid] += red[tid + off];
        __syncthreads();
    }
    float rstd = rsqrtf(red[0] * (1.0f / D) + 1e-5f);
    out[(size_t)row * D + tid]       = f2bf(d0 * rstd * w[tid]       + b[tid]);
    out[(size_t)row * D + tid + 256] = f2bf(d1 * rstd * w[tid + 256] + b[tid + 256]);
}

// Generic GEMM: C = mode( A[M,K](bf16) @ Wt[N,K](bf16) + bias (+resid) )
// 64x64 tile, BK=64, double-buffered LDS, 1 barrier/iter, reg prefetch.
#define GBM 64
#define GBN 64
#define GBK 64
#define LDG 72  // bf16 elems per row: 144B, 16B-aligned
__global__ __launch_bounds__(256) void gemm_bf16_kernel(
    const ushort_t* __restrict__ A, const ushort_t* __restrict__ Wt,
    const float* __restrict__ bias, const float* __restrict__ resid,
    void* __restrict__ Cout, int M, int K, int N, int mode) {
    __shared__ __align__(16) ushort_t As[2][GBM][LDG];
    __shared__ __align__(16) ushort_t Bs[2][GBN][LDG];
    int tid = threadIdx.x;
    int lane = tid & 63;
    int w = tid >> 6;
    int wr = w >> 1, wc = w & 1;
    int rowBase = blockIdx.y * GBM, colBase = blockIdx.x * GBN;
    int half = lane >> 4;
    int r16 = lane & 15;
    int sr = tid >> 2, sc = (tid & 3) * 16;

    const ushort_t* Arow = A + (size_t)(rowBase + sr) * K + sc;
    const ushort_t* Brow = Wt + (size_t)(colBase + sr) * K + sc;
    bf16x8 a0 = *(const bf16x8*)Arow, a1 = *(const bf16x8*)(Arow + 8);
    bf16x8 b0 = *(const bf16x8*)Brow, b1 = *(const bf16x8*)(Brow + 8);

    f32x4 acc[2][2];
    #pragma unroll
    for (int i = 0; i < 2; ++i)
        #pragma unroll
        for (int j = 0; j < 2; ++j)
            acc[i][j] = (f32x4){0.f, 0.f, 0.f, 0.f};

    int nIter = K / GBK;
    for (int it = 0; it < nIter; ++it) {
        int buf = it & 1;
        *(bf16x8*)&As[buf][sr][sc]     = a0;
        *(bf16x8*)&As[buf][sr][sc + 8] = a1;
        *(bf16x8*)&Bs[buf][sr][sc]     = b0;
        *(bf16x8*)&Bs[buf][sr][sc + 8] = b1;
        __syncthreads();
        if (it + 1 < nIter) {
            const ushort_t* An = Arow + (it + 1) * GBK;
            const ushort_t* Bn = Brow + (it + 1) * GBK;
            a0 = *(const bf16x8*)An; a1 = *(const bf16x8*)(An + 8);
            b0 = *(const bf16x8*)Bn; b1 = *(const bf16x8*)(Bn + 8);
        }
        #pragma unroll
        for (int ks = 0; ks < 2; ++ks)
            #pragma unroll
            for (int mi = 0; mi < 2; ++mi) {
                bf16x8 af = *(const bf16x8*)&As[buf][wr * 32 + mi * 16 + r16][ks * 32 + half * 8];
                #pragma unroll
                for (int ni = 0; ni < 2; ++ni) {
                    bf16x8 bfv = *(const bf16x8*)&Bs[buf][wc * 32 + ni * 16 + r16][ks * 32 + half * 8];
                    acc[mi][ni] = __builtin_amdgcn_mfma_f32_16x16x32_bf16(af, bfv, acc[mi][ni], 0, 0, 0);
                }
            }
    }
    #pragma unroll
    for (int mi = 0; mi < 2; ++mi) {
        #pragma unroll
        for (int ni = 0; ni < 2; ++ni) {
            int col = colBase + wc * 32 + ni * 16 + r16;
            float bc = bias ? bias[col] : 0.f;
            #pragma unroll
            for (int j = 0; j < 4; ++j) {
                int row = rowBase + wr * 32 + mi * 16 + half * 4 + j;
                float v = acc[mi][ni][j] + bc;
                if (mode == MODE_F32) {
                    if (resid) v += resid[(size_t)row * N + col];
                    ((float*)Cout)[(size_t)row * N + col] = v;
                } else {  // MODE_BF16_GELU
                    v = 0.5f * v * (1.0f + erff(v * 0.70710678118f));
                    ((ushort_t*)Cout)[(size_t)row * N + col] = f2bf(v);
                }
            }
        }
    }
}

// Fused QKV GEMM: A[T,512] @ Wqkv^T[1536,512] + bias, segmented epilogue:
// cols 0-511 -> Q (x0.125, bf16), 512-1023 -> K (bf16), 1024-1535 -> V^T.
__global__ __launch_bounds__(256) void gemm_qkv_kernel(
    const ushort_t* __restrict__ A, const ushort_t* __restrict__ Wt,
    const float* __restrict__ bq, const float* __restrict__ bk,
    const float* __restrict__ bv, ushort_t* __restrict__ Qb,
    ushort_t* __restrict__ Kb, ushort_t* __restrict__ Vt) {
    __shared__ __align__(16) ushort_t As[2][GBM][LDG];
    __shared__ __align__(16) ushort_t Bs[2][GBN][LDG];
    int tid = threadIdx.x;
    int lane = tid & 63;
    int w = tid >> 6;
    int wr = w >> 1, wc = w & 1;
    int rowBase = blockIdx.y * GBM, colBase = blockIdx.x * GBN;
    int half = lane >> 4;
    int r16 = lane & 15;
    int sr = tid >> 2, sc = (tid & 3) * 16;

    const ushort_t* Arow = A + (size_t)(rowBase + sr) * D + sc;
    const ushort_t* Brow = Wt + (size_t)(colBase + sr) * D + sc;
    bf16x8 a0 = *(const bf16x8*)Arow, a1 = *(const bf16x8*)(Arow + 8);
    bf16x8 b0 = *(const bf16x8*)Brow, b1 = *(const bf16x8*)(Brow + 8);

    f32x4 acc[2][2];
    #pragma unroll
    for (int i = 0; i < 2; ++i)
        #pragma unroll
        for (int j = 0; j < 2; ++j)
            acc[i][j] = (f32x4){0.f, 0.f, 0.f, 0.f};

    const int nIter = D / GBK;  // 8
    for (int it = 0; it < nIter; ++it) {
        int buf = it & 1;
        *(bf16x8*)&As[buf][sr][sc]     = a0;
        *(bf16x8*)&As[buf][sr][sc + 8] = a1;
        *(bf16x8*)&Bs[buf][sr][sc]     = b0;
        *(bf16x8*)&Bs[buf][sr][sc + 8] = b1;
        __syncthreads();
        if (it + 1 < nIter) {
            const ushort_t* An = Arow + (it + 1) * GBK;
            const ushort_t* Bn = Brow + (it + 1) * GBK;
            a0 = *(const bf16x8*)An; a1 = *(const bf16x8*)(An + 8);
            b0 = *(const bf16x8*)Bn; b1 = *(const bf16x8*)(Bn + 8);
        }
        #pragma unroll
        for (int ks = 0; ks < 2; ++ks)
            #pragma unroll
            for (int mi = 0; mi < 2; ++mi) {
                bf16x8 af = *(const bf16x8*)&As[buf][wr * 32 + mi * 16 + r16][ks * 32 + half * 8];
                #pragma unroll
                for (int ni = 0; ni < 2; ++ni) {
                    bf16x8 bfv = *(const bf16x8*)&Bs[buf][wc * 32 + ni * 16 + r16][ks * 32 + half * 8];
                    acc[mi][ni] = __builtin_amdgcn_mfma_f32_16x16x32_bf16(af, bfv, acc[mi][ni], 0, 0, 0);
                }
            }
    }
    int seg = colBase >> 9;          // 0:Q 1:K 2:V (block-uniform)
    int lcolB = (colBase & 511) + wc * 32;
    #pragma unroll
    for (int mi = 0; mi < 2; ++mi) {
        #pragma unroll
        for (int ni = 0; ni < 2; ++ni) {
            int col = lcolB + ni * 16 + r16;
            int row0 = rowBase + wr * 32 + mi * 16 + half * 4;
            if (seg == 0) {
                float bc = bq[col];
                #pragma unroll
                for (int j = 0; j < 4; ++j)
                    Qb[(size_t)(row0 + j) * D + col] = f2bf((acc[mi][ni][j] + bc) * 0.125f);
            } else if (seg == 1) {
                float bc = bk[col];
                #pragma unroll
                for (int j = 0; j < 4; ++j)
                    Kb[(size_t)(row0 + j) * D + col] = f2bf(acc[mi][ni][j] + bc);
            } else {
                float bc = bv[col];
                u16x4 p;
                #pragma unroll
                for (int j = 0; j < 4; ++j) p[j] = f2bf(acc[mi][ni][j] + bc);
                *(u16x4*)&Vt[(size_t)col * T + row0] = p;
            }
        }
    }
}

// Fused flash attention, swapped-operand softmax; 2-wave blocks (QBLK=32)
// for 2+ independent blocks/CU -> cross-block MFMA/VALU overlap.
#define QBLK 32
#define JBLK 64
#define APAD 72
__global__ __launch_bounds__(128) void flash_attn_kernel(
    const ushort_t* __restrict__ Q, const ushort_t* __restrict__ Kb,
    const ushort_t* __restrict__ Vt, ushort_t* __restrict__ Y) {
    __shared__ __align__(16) ushort_t Qs[QBLK][APAD];     // [q][d]
    __shared__ __align__(16) ushort_t Ks[2][JBLK][APAD];  // [j][d]
    __shared__ __align__(16) ushort_t Vs[2][DH][APAD];    // [d][j]
    int h = blockIdx.y;
    int qBase = blockIdx.x * QBLK;
    int tid = threadIdx.x;
    int lane = tid & 63;
    int w = tid >> 6;          // 0..1
    int r16 = lane & 15;
    int half = lane >> 4;
    int sq = tid >> 2, sq16 = (tid & 3) * 16;   // Q staging: 32 rows x 64
    int sr = tid >> 1, sc32 = (tid & 1) * 32;   // K/V staging: 64 rows x 64

    {
        const ushort_t* src = Q + (size_t)(qBase + sq) * D + h * DH + sq16;
        *(bf16x8*)&Qs[sq][sq16]     = *(const bf16x8*)src;
        *(bf16x8*)&Qs[sq][sq16 + 8] = *(const bf16x8*)(src + 8);
    }
    // prefetch K/V tile 0 into regs (32 elems each)
    bf16x8 kr[4], vr[4];
    {
        const ushort_t* ks_ = Kb + (size_t)sr * D + h * DH + sc32;
        const ushort_t* vs_ = Vt + (size_t)(h * DH + sr) * T + sc32;
        #pragma unroll
        for (int i = 0; i < 4; ++i) {
            kr[i] = *(const bf16x8*)(ks_ + i * 8);
            vr[i] = *(const bf16x8*)(vs_ + i * 8);
        }
    }
    __syncthreads();
    // hoist Q frags (loop-invariant): B-operand cols = q = w*16 + r16
    bf16x8 qf0 = *(const bf16x8*)&Qs[w * 16 + r16][half * 8];
    bf16x8 qf1 = *(const bf16x8*)&Qs[w * 16 + r16][32 + half * 8];

    f32x4 o_acc[4];
    #pragma unroll
    for (int i = 0; i < 4; ++i) o_acc[i] = (f32x4){0.f, 0.f, 0.f, 0.f};
    float m_run = -3e38f, l_run = 0.f;

    // PV shuffle sources: values for q-row r16 live on lanes {r16+16*s}
    int srcE = r16 + 32 * (half & 1);
    int srcO = srcE + 16;

    const int NT = T / JBLK;
    for (int jt = 0; jt < NT; ++jt) {
        int buf = jt & 1;
        #pragma unroll
        for (int i = 0; i < 4; ++i) {
            *(bf16x8*)&Ks[buf][sr][sc32 + i * 8] = kr[i];
            *(bf16x8*)&Vs[buf][sr][sc32 + i * 8] = vr[i];
        }
        __syncthreads();
        if (jt + 1 < NT) {
            int jB = (jt + 1) * JBLK;
            const ushort_t* ks_ = Kb + (size_t)(jB + sr) * D + h * DH + sc32;
            const ushort_t* vs_ = Vt + (size_t)(h * DH + sr) * T + jB + sc32;
            #pragma unroll
            for (int i = 0; i < 4; ++i) {
                kr[i] = *(const bf16x8*)(ks_ + i * 8);
                vr[i] = *(const bf16x8*)(vs_ + i * 8);
            }
        }
        // S^T(64x16) = K_tile @ Q^T : s[ni][reg] = S[q][k=ni*16+half*4+reg]
        f32x4 s[4];
        #pragma unroll
        for (int ni = 0; ni < 4; ++ni) s[ni] = (f32x4){0.f, 0.f, 0.f, 0.f};
        __builtin_amdgcn_s_setprio(1);
        #pragma unroll
        for (int ni = 0; ni < 4; ++ni) {
            bf16x8 kf0 = *(const bf16x8*)&Ks[buf][ni * 16 + r16][half * 8];
            bf16x8 kf1 = *(const bf16x8*)&Ks[buf][ni * 16 + r16][32 + half * 8];
            s[ni] = __builtin_amdgcn_mfma_f32_16x16x32_bf16(kf0, qf0, s[ni], 0, 0, 0);
            s[ni] = __builtin_amdgcn_mfma_f32_16x16x32_bf16(kf1, qf1, s[ni], 0, 0, 0);
        }
        __builtin_amdgcn_s_setprio(0);
        // lane-local softmax + cross-half reduce
        float mx = s[0][0];
        #pragma unroll
        for (int ni = 0; ni < 4; ++ni)
            #pragma unroll
            for (int j = 0; j < 4; ++j) mx = fmaxf(mx, s[ni][j]);
        mx = fmaxf(mx, __shfl_xor(mx, 16));
        mx = fmaxf(mx, __shfl_xor(mx, 32));
        float mn = fmaxf(m_run, mx);
        float alpha = __expf(m_run - mn);
        m_run = mn;
        float p[4][4];
        float lsum = 0.f;
        #pragma unroll
        for (int ni = 0; ni < 4; ++ni)
            #pragma unroll
            for (int j = 0; j < 4; ++j) {
                p[ni][j] = __expf(s[ni][j] - mn);
                lsum += p[ni][j];
            }
        lsum += __shfl_xor(lsum, 16);
        lsum += __shfl_xor(lsum, 32);
        l_run = l_run * alpha + lsum;
        #pragma unroll
        for (int ni = 0; ni < 4; ++ni)
            #pragma unroll
            for (int j = 0; j < 4; ++j) o_acc[ni][j] *= alpha;
        // pack P to bf16 pairs
        unsigned int q_lo[4], q_hi[4];
        #pragma unroll
        for (int ni = 0; ni < 4; ++ni) {
            q_lo[ni] = (unsigned)f2bf(p[ni][0]) | ((unsigned)f2bf(p[ni][1]) << 16);
            q_hi[ni] = (unsigned)f2bf(p[ni][2]) | ((unsigned)f2bf(p[ni][3]) << 16);
        }
        // PV swapped: O^T += V^T @ P^T ; B-frag built via shuffles
        #pragma unroll
        for (int ks = 0; ks < 2; ++ks) {
            unsigned a0 = __shfl((int)q_lo[2 * ks], srcE);
            unsigned a1 = __shfl((int)q_hi[2 * ks], srcE);
            unsigned b0 = __shfl((int)q_lo[2 * ks], srcO);
            unsigned b1 = __shfl((int)q_hi[2 * ks], srcO);
            unsigned c0 = __shfl((int)q_lo[2 * ks + 1], srcE);
            unsigned c1 = __shfl((int)q_hi[2 * ks + 1], srcE);
            unsigned d0 = __shfl((int)q_lo[2 * ks + 1], srcO);
            unsigned d1 = __shfl((int)q_hi[2 * ks + 1], srcO);
            u32x4 fp;
            fp[0] = (half < 2) ? a0 : c0;
            fp[1] = (half < 2) ? a1 : c1;
            fp[2] = (half < 2) ? b0 : d0;
            fp[3] = (half < 2) ? b1 : d1;
            bf16x8 pb = __builtin_bit_cast(bf16x8, fp);
            __builtin_amdgcn_s_setprio(1);
            #pragma unroll
            for (int ni = 0; ni < 4; ++ni) {
                bf16x8 vf = *(const bf16x8*)&Vs[buf][ni * 16 + r16][ks * 32 + half * 8];
                o_acc[ni] = __builtin_amdgcn_mfma_f32_16x16x32_bf16(vf, pb, o_acc[ni], 0, 0, 0);
            }
            __builtin_amdgcn_s_setprio(0);
        }
    }
    // epilogue: lane holds O[q = qBase+w*16+r16][d = ni*16+half*4+reg]
    float inv = 1.0f / l_run;
    int qrow = qBase + w * 16 + r16;
    #pragma unroll
    for (int ni = 0; ni < 4; ++ni) {
        u16x4 pk;
        #pragma unroll
        for (int j = 0; j < 4; ++j) pk[j] = f2bf(o_acc[ni][j] * inv);
        *(u16x4*)&Y[(size_t)qrow * D + h * DH + ni * 16 + half * 4] = pk;
    }
}

extern "C" void kernel_launch(void* const* d_in, const int* in_sizes, int n_in,
                              void* d_out, int out_size, void* d_ws, size_t ws_size,
                              hipStream_t stream) {
    const float* seq  = (const float*)d_in[0];
    const float* pos  = (const float*)d_in[1];
    const float* Wq   = (const float*)d_in[2];
    const float* bq   = (const float*)d_in[3];
    const float* Wk   = (const float*)d_in[4];
    const float* bk   = (const float*)d_in[5];
    const float* Wv   = (const float*)d_in[6];
    const float* bv   = (const float*)d_in[7];
    const float* Wp   = (const float*)d_in[8];
    const float* bp   = (const float*)d_in[9];
    const float* W1   = (const float*)d_in[10];
    const float* b1   = (const float*)d_in[11];
    const float* W2   = (const float*)d_in[12];
    const float* b2   = (const float*)d_in[13];
    const float* ln1w = (const float*)d_in[14];
    const float* ln1b = (const float*)d_in[15];
    const float* ln2w = (const float*)d_in[16];
    const float* ln2b = (const float*)d_in[17];
    const float* lnfw = (const float*)d_in[18];
    const float* lnfb = (const float*)d_in[19];
    const float* Whead = (const float*)d_in[20];
    float* out = (float*)d_out;

    float* ws = (float*)d_ws;
    const size_t SZ = (size_t)T * D;   // 1,048,576 floats
    const size_t HS = SZ / 2;          // one bf16 T*D buffer, in float units
    float*    X     = ws;                               // [0, SZ)
    ushort_t* Hb    = (ushort_t*)(ws + SZ);             // +HS
    ushort_t* Qb    = (ushort_t*)(ws + SZ + HS);        // +HS
    ushort_t* Kb    = (ushort_t*)(ws + SZ + 2 * HS);    // +HS
    ushort_t* Vt    = (ushort_t*)(ws + SZ + 3 * HS);    // +HS
    ushort_t* Yb    = (ushort_t*)(ws + SZ + 4 * HS);    // +HS
    ushort_t* M1    = Qb;  // T x 4D bf16, aliases Qb..Yb (dead by then)
    ushort_t* WqkvT = (ushort_t*)(ws + SZ + 5 * HS);    // NL*1536*512 bf16 = 3HS
    ushort_t* WpT   = (ushort_t*)(ws + SZ + 8 * HS);    // NL*D*D bf16 = 1HS
    ushort_t* W1T   = (ushort_t*)(ws + SZ + 9 * HS);    // NL*D*4D bf16 = 4HS
    ushort_t* W2T   = (ushort_t*)(ws + SZ + 13 * HS);   // 4HS
    ushort_t* WhT   = (ushort_t*)(ws + SZ + 17 * HS);   // 0.25HS

    const size_t qkvZ = (size_t)1536 * 512;
    dim3 b256(256);
    wt_kernel<<<dim3(16, 16, NL), b256, 0, stream>>>(Wq, WqkvT, D, D, (size_t)D * D, qkvZ);
    wt_kernel<<<dim3(16, 16, NL), b256, 0, stream>>>(Wk, WqkvT + 512 * 512, D, D, (size_t)D * D, qkvZ);
    wt_kernel<<<dim3(16, 16, NL), b256, 0, stream>>>(Wv, WqkvT + 1024 * 512, D, D, (size_t)D * D, qkvZ);
    wt_kernel<<<dim3(16, 16, NL), b256, 0, stream>>>(Wp, WpT, D, D, (size_t)D * D, (size_t)D * D);
    wt_kernel<<<dim3(64, 16, NL), b256, 0, stream>>>(W1, W1T, D, 4 * D, (size_t)D * 4 * D, (size_t)D * 4 * D);
    wt_kernel<<<dim3(16, 64, NL), b256, 0, stream>>>(W2, W2T, 4 * D, D, (size_t)4 * D * D, (size_t)4 * D * D);
    wt_kernel<<<dim3(16, 16, 1), b256, 0, stream>>>(Whead, WhT, D, D, 0, 0);

    add_pos_kernel<<<(T * D + 255) / 256, b256, 0, stream>>>(seq, pos, X, T * D);

    for (int l = 0; l < NL; ++l) {
        size_t wo = (size_t)l * D * D;
        size_t wo1 = (size_t)l * D * 4 * D;
        layernorm_kernel<<<T, b256, 0, stream>>>(X, ln1w + l * D, ln1b + l * D, Hb);
        gemm_qkv_kernel<<<dim3(24, T / GBM), b256, 0, stream>>>(
            Hb, WqkvT + l * qkvZ, bq + l * D, bk + l * D, bv + l * D, Qb, Kb, Vt);
        flash_attn_kernel<<<dim3(T / QBLK, NH), dim3(128), 0, stream>>>(Qb, Kb, Vt, Yb);
        gemm_bf16_kernel<<<dim3(D / GBN, T / GBM), b256, 0, stream>>>(
            Yb, WpT + wo, bp + l * D, X, X, T, D, D, MODE_F32);
        layernorm_kernel<<<T, b256, 0, stream>>>(X, ln2w + l * D, ln2b + l * D, Hb);
        gemm_bf16_kernel<<<dim3(4 * D / GBN, T / GBM), b256, 0, stream>>>(
            Hb, W1T + wo1, b1 + l * 4 * D, nullptr, M1, T, D, 4 * D, MODE_BF16_GELU);
        gemm_bf16_kernel<<<dim3(D / GBN, T / GBM), b256, 0, stream>>>(
            M1, W2T + wo1, b2 + l * D, X, X, T, 4 * D, D, MODE_F32);
    }
    layernorm_kernel<<<T, b256, 0, stream>>>(X, lnfw, lnfb, Hb);
    gemm_bf16_kernel<<<dim3(D / GBN, T / GBM), b256, 0, stream>>>(
        Hb, WhT, nullptr, nullptr, out, T, D, D, MODE_F32);
}